// Round 9
// baseline (231.474 us; speedup 1.0000x reference)
//
#include <hip/hip_runtime.h>

// Problem: B=32, C=3, H=512, W=512 -> NIMG = 96 flat images
// R9 structure: DYNAMIC tile scheduling. Grid 1792 = 256 CU x 7 resident
//   blocks (LDS 20,480 B -> empirically max 7/CU; R8 proved 8 do NOT fit).
//   Each block pulls tile indices from an atomicAdd counter in d_ws until the
//   3072 tiles (96 img x 32) are gone. Work-conserving: no slot idles while
//   tiles remain -> makespan ~12T/7 vs static-R2's 2T (86% packing ceiling).
//   Blocks also desynchronize (phase mixing on each CU).
// Tile body = R2/R4 proven 8x16-pooled tile, bit-identical numerics:
//   phase 0: Haar DWT -> cA 38x70 in LDS (zero-pad OOB); interior 32x64
//            cH/cV written straight to d_out high region.
//   phase a/b (x4 ic-chunks): conv1(1->16)+relu+pool2 -> LDS, conv2(16->8) acc.
//   epilogue: relu+pool2 (h2 exchange via LDS), conv3(8->4,1x1) -> d_out low.
// R1: conv1/conv2 use v_pk_fma_f32 (packed fp32, 2 FMA/instr) over oc pairs
//   (SGPR weight pairs, free activation broadcast via VOP3P op_sel).
// R7 lesson kept: UNBALANCED task loops (execz-skip beats balanced-with-mask).
// __launch_bounds__(256,7): VGPR cap 73 (avoids R4's cap-32 remat penalty).

typedef float v2f __attribute__((ext_vector_type(2)));

// acc(pair over oc) += w(pair over oc, SGPR) * broadcast(data.word0)
#define PK_FMA_W0(acc, w, d) \
    asm("v_pk_fma_f32 %0, %1, %2, %0 op_sel:[0,0,0] op_sel_hi:[1,0,1]" \
        : "+v"(acc) : "s"(w), "v"(d))
// acc += w * broadcast(data.word1)
#define PK_FMA_W1(acc, w, d) \
    asm("v_pk_fma_f32 %0, %1, %2, %0 op_sel:[0,1,0] op_sel_hi:[1,1,1]" \
        : "+v"(acc) : "s"(w), "v"(d))
// dst = w * broadcast(data.word0)   (accumulator init without v_mov zeroing)
#define PK_MUL_W0(dst, w, d) \
    asm("v_pk_mul_f32 %0, %1, %2 op_sel:[0,0] op_sel_hi:[1,0]" \
        : "=v"(dst) : "s"(w), "v"(d))
#define PK_MUL_W1(dst, w, d) \
    asm("v_pk_mul_f32 %0, %1, %2 op_sel:[0,1] op_sel_hi:[1,1]" \
        : "=v"(dst) : "s"(w), "v"(d))

__global__ __launch_bounds__(256, 7) void fused_all_kernel(
    const float* __restrict__ x,
    const float* __restrict__ w1, const float* __restrict__ b1,
    const float* __restrict__ w2, const float* __restrict__ b2,
    const float* __restrict__ w3, const float* __restrict__ b3,
    float* __restrict__ outLow, float* __restrict__ outHigh,
    unsigned int* __restrict__ counter)
{
    __shared__ __align__(16) float ca[38 * 70];      // cA tile, rows stride 70
    __shared__ __align__(16) float h1s[4 * 18 * 34]; // conv1 chunk (reused for h2 xchg)
    __shared__ int s_tile;

    int tid = threadIdx.x;

    for (;;) {
        if (tid == 0) s_tile = (int)atomicAdd(counter, 1u);
        __syncthreads();   // broadcast s_tile; also orders prev tile's LDS reads
                           // (hx2) before this tile's ca/h1s writes
        int tIdx = s_tile;
        if (tIdx >= 3072) break;

        int img  = tIdx >> 5;
        int t    = tIdx & 31;
        int tyy = t >> 2, txx = t & 3;         // 8 pooled rows x 16 cols
        int hy0 = tyy * 16 - 1, hx0 = txx * 32 - 1; // h1 tile origin (18x34 incl halo)
        int cy0 = tyy * 32 - 3, cx0 = txx * 64 - 3; // cA tile origin (38x70)

        const float* xi = x + img * 262144;
        float* hb = outHigh + img * 131072;

        // ---- Phase 0a: interior 32x64 cA (coalesced), cH/cV -> global ----
        #pragma unroll
        for (int k = 0; k < 2; ++k) {
            int i = tid + k * 256;
            int row = i >> 4, cg = i & 15;
            int gy = tyy * 32 + row;
            int gx = txx * 64 + cg * 4;
            const float* r0 = xi + (2 * gy) * 512 + 2 * gx;
            const float* r1 = r0 + 512;
            float4 t0 = *(const float4*)(r0);
            float4 t1 = *(const float4*)(r0 + 4);
            float4 u0 = *(const float4*)(r1);
            float4 u1 = *(const float4*)(r1 + 4);
            float4 vA, vH, vV;
            vA.x = (t0.x + t0.y + u0.x + u0.y) * 0.5f;
            vH.x = (t0.x + t0.y - u0.x - u0.y) * 0.5f;
            vV.x = (t0.x - t0.y + u0.x - u0.y) * 0.5f;
            vA.y = (t0.z + t0.w + u0.z + u0.w) * 0.5f;
            vH.y = (t0.z + t0.w - u0.z - u0.w) * 0.5f;
            vV.y = (t0.z - t0.w + u0.z - u0.w) * 0.5f;
            vA.z = (t1.x + t1.y + u1.x + u1.y) * 0.5f;
            vH.z = (t1.x + t1.y - u1.x - u1.y) * 0.5f;
            vV.z = (t1.x - t1.y + u1.x - u1.y) * 0.5f;
            vA.w = (t1.z + t1.w + u1.z + u1.w) * 0.5f;
            vH.w = (t1.z + t1.w - u1.z - u1.w) * 0.5f;
            vV.w = (t1.z - t1.w + u1.z - u1.w) * 0.5f;
            int po = (gy << 8) + gx;
            *(float4*)(hb + po) = vH;
            *(float4*)(hb + 65536 + po) = vV;
            float* cp = ca + (row + 3) * 70 + cg * 4 + 3;
            cp[0] = vA.x; cp[1] = vA.y; cp[2] = vA.z; cp[3] = vA.w;
        }

        // ---- Phase 0b: 3-wide halo ring of cA (612 points), vA only ----
        // Ring = rows {0,1,2} + {35,36,37} (full width 70) + rows 3..34 with
        // cols {0,1,2,67,68,69}. Unbalanced stride-256 (execz-skips pass 3).
        #pragma unroll 1
        for (int i = tid; i < 612; i += 256) {
            int r, c;
            if (i < 210)      { r = i / 70;              c = i - r * 70; }
            else if (i < 420) { int j = i - 210; r = 35 + j / 70; c = j - (j / 70) * 70; }
            else              { int j = i - 420; r = 3 + j / 6; int k6 = j - (j / 6) * 6;
                                c = (k6 < 3) ? k6 : (64 + k6); }   // {0,1,2,67,68,69}
            int gy = cy0 + r, gx = cx0 + c;
            float v = 0.f;
            if ((unsigned)gy < 256u && (unsigned)gx < 256u) {
                const float* p0 = xi + (2 * gy) * 512 + 2 * gx;
                float2 a = *(const float2*)(p0);
                float2 b = *(const float2*)(p0 + 512);
                v = (a.x + a.y + b.x + b.y) * 0.5f;
            }
            ca[r * 70 + c] = v;
        }

        int pos = tid & 127;
        int ocg = __builtin_amdgcn_readfirstlane(tid >> 7);
        int ly = pos >> 4, lx = pos & 15;

        v2f acc2[2][2][2];
        #pragma unroll
        for (int o2 = 0; o2 < 2; ++o2)
            #pragma unroll
            for (int r = 0; r < 2; ++r)
                #pragma unroll
                for (int c = 0; c < 2; ++c) acc2[o2][r][c] = (v2f){0.f, 0.f};

        __syncthreads();   // ca ready

        #pragma unroll 1
        for (int cc = 0; cc < 4; ++cc) {
            v2f wp1[2][9];
            #pragma unroll
            for (int o2 = 0; o2 < 2; ++o2)
                #pragma unroll
                for (int k = 0; k < 9; ++k)
                    wp1[o2][k] = (v2f){ w1[(cc * 4 + o2 * 2    ) * 9 + k],
                                        w1[(cc * 4 + o2 * 2 + 1) * 9 + k] };
            if (cc) __syncthreads();   // prev chunk's conv2 reads before overwrite

            // Phase a: h1 chunk = pool2(relu(conv1)), 4 oc, 18x34 (incl halo)
            #pragma unroll 1
            for (int i = tid; i < 612; i += 256) {
                int hy = i / 34, hx = i - hy * 34;
                const float* pb = ca + (2 * hy) * 70 + 2 * hx;
                v2f pr[4][2];
                #pragma unroll
                for (int r = 0; r < 4; ++r) {
                    pr[r][0] = *(const v2f*)(pb + r * 70);
                    pr[r][1] = *(const v2f*)(pb + r * 70 + 2);
                }
                bool oob = ((unsigned)(hy0 + hy) >= 128u) | ((unsigned)(hx0 + hx) >= 128u);
                v2f am[2][4];   // [ocpair][pos: p00 p01 p10 p11]
                #pragma unroll
                for (int ky = 0; ky < 3; ++ky)
                #pragma unroll
                for (int kx = 0; kx < 3; ++kx) {
                    #pragma unroll
                    for (int o2 = 0; o2 < 2; ++o2)
                    #pragma unroll
                    for (int dy = 0; dy < 2; ++dy)
                    #pragma unroll
                    for (int dx = 0; dx < 2; ++dx) {
                        v2f d = pr[ky + dy][(kx + dx) >> 1];
                        if (ky == 0 && kx == 0) {
                            if (((kx + dx) & 1) == 0) PK_MUL_W0(am[o2][dy * 2 + dx], wp1[o2][0], d);
                            else                      PK_MUL_W1(am[o2][dy * 2 + dx], wp1[o2][0], d);
                        } else {
                            if (((kx + dx) & 1) == 0) PK_FMA_W0(am[o2][dy * 2 + dx], wp1[o2][ky * 3 + kx], d);
                            else                      PK_FMA_W1(am[o2][dy * 2 + dx], wp1[o2][ky * 3 + kx], d);
                        }
                    }
                }
                #pragma unroll
                for (int o2 = 0; o2 < 2; ++o2) {
                    float mx = fmaxf(fmaxf(am[o2][0].x, am[o2][1].x),
                                     fmaxf(am[o2][2].x, am[o2][3].x));
                    float my = fmaxf(fmaxf(am[o2][0].y, am[o2][1].y),
                                     fmaxf(am[o2][2].y, am[o2][3].y));
                    mx = fmaxf(mx + b1[cc * 4 + o2 * 2    ], 0.f);
                    my = fmaxf(my + b1[cc * 4 + o2 * 2 + 1], 0.f);
                    h1s[((o2 * 2    ) * 18 + hy) * 34 + hx] = oob ? 0.f : mx;
                    h1s[((o2 * 2 + 1) * 18 + hy) * 34 + hx] = oob ? 0.f : my;
                }
            }
            __syncthreads();

            // Phase b: conv2 accumulate over these 4 input channels (4 oc/group)
            #pragma unroll
            for (int icl = 0; icl < 4; ++icl) {
                int ic = cc * 4 + icl;
                v2f wl[2][9];   // weight pairs hoisted ahead of ds_reads
                #pragma unroll
                for (int o2 = 0; o2 < 2; ++o2) {
                    int oc0 = ocg * 4 + o2 * 2;
                    #pragma unroll
                    for (int k = 0; k < 9; ++k)
                        wl[o2][k] = (v2f){ w2[((oc0    ) * 16 + ic) * 9 + k],
                                           w2[((oc0 + 1) * 16 + ic) * 9 + k] };
                }
                const float* base = h1s + (icl * 18 + ly * 2) * 34 + lx * 2;
                v2f wr[4][2];
                #pragma unroll
                for (int r = 0; r < 4; ++r) {
                    wr[r][0] = *(const v2f*)(base + r * 34);
                    wr[r][1] = *(const v2f*)(base + r * 34 + 2);
                }
                #pragma unroll
                for (int ky = 0; ky < 3; ++ky)
                #pragma unroll
                for (int kx = 0; kx < 3; ++kx)
                #pragma unroll
                for (int o2 = 0; o2 < 2; ++o2) {
                    #pragma unroll
                    for (int r = 0; r < 2; ++r)
                    #pragma unroll
                    for (int c = 0; c < 2; ++c) {
                        v2f d = wr[r + ky][(c + kx) >> 1];
                        if (((c + kx) & 1) == 0) PK_FMA_W0(acc2[o2][r][c], wl[o2][ky * 3 + kx], d);
                        else                     PK_FMA_W1(acc2[o2][r][c], wl[o2][ky * 3 + kx], d);
                    }
                }
            }
        }

        // Epilogue: bias+relu+pool2 of conv2, LDS exchange, conv3 -> low
        float h2v[4];
        #pragma unroll
        for (int o2 = 0; o2 < 2; ++o2) {
            float mx = fmaxf(fmaxf(acc2[o2][0][0].x, acc2[o2][0][1].x),
                             fmaxf(acc2[o2][1][0].x, acc2[o2][1][1].x));
            float my = fmaxf(fmaxf(acc2[o2][0][0].y, acc2[o2][0][1].y),
                             fmaxf(acc2[o2][1][0].y, acc2[o2][1][1].y));
            h2v[o2 * 2    ] = fmaxf(mx + b2[ocg * 4 + o2 * 2    ], 0.f);
            h2v[o2 * 2 + 1] = fmaxf(my + b2[ocg * 4 + o2 * 2 + 1], 0.f);
        }
        __syncthreads();                 // conv2 done reading h1s; reuse for h2
        float* hx2 = h1s;                // [128 pos][9] stride 9 -> conflict-free
        #pragma unroll
        for (int j = 0; j < 4; ++j) hx2[pos * 9 + ocg * 4 + j] = h2v[j];
        __syncthreads();

        float hv[8];
        #pragma unroll
        for (int ic = 0; ic < 8; ++ic) hv[ic] = hx2[pos * 9 + ic];
        float* dst = outLow + img * 16384;
        int posg = (tyy * 8 + ly) * 64 + txx * 16 + lx;
        #pragma unroll
        for (int jo = 0; jo < 2; ++jo) {
            int oc3 = ocg * 2 + jo;
            float s = b3[oc3];
            #pragma unroll
            for (int ic = 0; ic < 8; ++ic) s += w3[oc3 * 8 + ic] * hv[ic];
            dst[oc3 * 4096 + posg] = s;
        }
        // loop back: next atomic fetch; top barrier orders hx2 reads vs new writes
    }
}

extern "C" void kernel_launch(void* const* d_in, const int* in_sizes, int n_in,
                              void* d_out, int out_size, void* d_ws, size_t ws_size,
                              hipStream_t stream) {
    const float* x  = (const float*)d_in[0];
    const float* w1 = (const float*)d_in[1];
    const float* b1 = (const float*)d_in[2];
    const float* w2 = (const float*)d_in[3];
    const float* b2 = (const float*)d_in[4];
    const float* w3 = (const float*)d_in[5];
    const float* b3 = (const float*)d_in[6];
    float* out     = (float*)d_out;
    float* outLow  = out;                 // 1,572,864 floats
    float* outHigh = out + 1572864;       // 12,582,912 floats
    unsigned int* counter = (unsigned int*)d_ws;

    hipMemsetAsync(counter, 0, sizeof(unsigned int), stream);
    fused_all_kernel<<<1792, 256, 0, stream>>>(x, w1, b1, w2, b2, w3, b3,
                                               outLow, outHigh, counter);
}

// Round 10
// 208.608 us; speedup vs baseline: 1.1096x; 1.1096x over previous
//
#include <hip/hip_runtime.h>

// Problem: B=32, C=3, H=512, W=512 -> NIMG = 96 flat images
// R10 = recombination of measured optima (R9's dynamic scheduling REVERTED —
//   HW dispatcher already backfills; atomics only added startup serialization):
//   - static grid 3072 (12 blocks/CU, scheduler backfills 7-8 slots)
//   - R2 8x16-pooled tile geometry + UNBALANCED stride-256 task loops
//     (execz-skip beats balanced-with-mask: R4/R6 busy +12%)
//   - LDS 20,480 B (stride 70/34, R4 layout; occ 66 vs R2's 57)
//   - __launch_bounds__(256,7): R9 proved this body compiles at VGPR 36 with
//     it (no R4-style cap-32 rematerialization)
// Per tile:
//   phase 0: Haar DWT -> cA 38x70 in LDS (zero-pad OOB); interior 32x64
//            cH/cV written straight to d_out high region.
//   phase a/b (x4 ic-chunks): conv1(1->16)+relu+pool2 -> LDS, conv2(16->8) acc.
//   epilogue: relu+pool2 (h2 exchange via LDS), conv3(8->4,1x1) -> d_out low.
// R1: conv1/conv2 use v_pk_fma_f32 (packed fp32, 2 FMA/instr) over oc pairs
//   (SGPR weight pairs, free activation broadcast via VOP3P op_sel).
// Numerics bit-identical to R2/R4/R9 (absmax 0.015625).

typedef float v2f __attribute__((ext_vector_type(2)));

// acc(pair over oc) += w(pair over oc, SGPR) * broadcast(data.word0)
#define PK_FMA_W0(acc, w, d) \
    asm("v_pk_fma_f32 %0, %1, %2, %0 op_sel:[0,0,0] op_sel_hi:[1,0,1]" \
        : "+v"(acc) : "s"(w), "v"(d))
// acc += w * broadcast(data.word1)
#define PK_FMA_W1(acc, w, d) \
    asm("v_pk_fma_f32 %0, %1, %2, %0 op_sel:[0,1,0] op_sel_hi:[1,1,1]" \
        : "+v"(acc) : "s"(w), "v"(d))
// dst = w * broadcast(data.word0)   (accumulator init without v_mov zeroing)
#define PK_MUL_W0(dst, w, d) \
    asm("v_pk_mul_f32 %0, %1, %2 op_sel:[0,0] op_sel_hi:[1,0]" \
        : "=v"(dst) : "s"(w), "v"(d))
#define PK_MUL_W1(dst, w, d) \
    asm("v_pk_mul_f32 %0, %1, %2 op_sel:[0,1] op_sel_hi:[1,1]" \
        : "=v"(dst) : "s"(w), "v"(d))

__global__ __launch_bounds__(256, 7) void fused_all_kernel(
    const float* __restrict__ x,
    const float* __restrict__ w1, const float* __restrict__ b1,
    const float* __restrict__ w2, const float* __restrict__ b2,
    const float* __restrict__ w3, const float* __restrict__ b3,
    float* __restrict__ outLow, float* __restrict__ outHigh)
{
    __shared__ __align__(16) float ca[38 * 70];      // cA tile, rows stride 70
    __shared__ __align__(16) float h1s[4 * 18 * 34]; // conv1 chunk (reused for h2 xchg)

    int tid = threadIdx.x;

    int tIdx = blockIdx.x;                 // 0..3071
    int img  = tIdx >> 5;
    int t    = tIdx & 31;
    int tyy = t >> 2, txx = t & 3;         // 8 pooled rows x 16 cols
    int hy0 = tyy * 16 - 1, hx0 = txx * 32 - 1; // h1 tile origin (18x34 incl halo)
    int cy0 = tyy * 32 - 3, cx0 = txx * 64 - 3; // cA tile origin (38x70)

    const float* xi = x + img * 262144;
    float* hb = outHigh + img * 131072;

    // ---- Phase 0a: interior 32x64 cA (coalesced), cH/cV -> global ----
    #pragma unroll
    for (int k = 0; k < 2; ++k) {
        int i = tid + k * 256;
        int row = i >> 4, cg = i & 15;
        int gy = tyy * 32 + row;
        int gx = txx * 64 + cg * 4;
        const float* r0 = xi + (2 * gy) * 512 + 2 * gx;
        const float* r1 = r0 + 512;
        float4 t0 = *(const float4*)(r0);
        float4 t1 = *(const float4*)(r0 + 4);
        float4 u0 = *(const float4*)(r1);
        float4 u1 = *(const float4*)(r1 + 4);
        float4 vA, vH, vV;
        vA.x = (t0.x + t0.y + u0.x + u0.y) * 0.5f;
        vH.x = (t0.x + t0.y - u0.x - u0.y) * 0.5f;
        vV.x = (t0.x - t0.y + u0.x - u0.y) * 0.5f;
        vA.y = (t0.z + t0.w + u0.z + u0.w) * 0.5f;
        vH.y = (t0.z + t0.w - u0.z - u0.w) * 0.5f;
        vV.y = (t0.z - t0.w + u0.z - u0.w) * 0.5f;
        vA.z = (t1.x + t1.y + u1.x + u1.y) * 0.5f;
        vH.z = (t1.x + t1.y - u1.x - u1.y) * 0.5f;
        vV.z = (t1.x - t1.y + u1.x - u1.y) * 0.5f;
        vA.w = (t1.z + t1.w + u1.z + u1.w) * 0.5f;
        vH.w = (t1.z + t1.w - u1.z - u1.w) * 0.5f;
        vV.w = (t1.z - t1.w + u1.z - u1.w) * 0.5f;
        int po = (gy << 8) + gx;
        *(float4*)(hb + po) = vH;
        *(float4*)(hb + 65536 + po) = vV;
        float* cp = ca + (row + 3) * 70 + cg * 4 + 3;
        cp[0] = vA.x; cp[1] = vA.y; cp[2] = vA.z; cp[3] = vA.w;
    }

    // ---- Phase 0b: 3-wide halo ring of cA (612 points), vA only ----
    // Ring = rows {0,1,2} + {35,36,37} (full width 70) + rows 3..34 with
    // cols {0,1,2,67,68,69}. Unbalanced stride-256 (execz-skips pass 3).
    #pragma unroll 1
    for (int i = tid; i < 612; i += 256) {
        int r, c;
        if (i < 210)      { r = i / 70;              c = i - r * 70; }
        else if (i < 420) { int j = i - 210; r = 35 + j / 70; c = j - (j / 70) * 70; }
        else              { int j = i - 420; r = 3 + j / 6; int k6 = j - (j / 6) * 6;
                            c = (k6 < 3) ? k6 : (64 + k6); }   // {0,1,2,67,68,69}
        int gy = cy0 + r, gx = cx0 + c;
        float v = 0.f;
        if ((unsigned)gy < 256u && (unsigned)gx < 256u) {
            const float* p0 = xi + (2 * gy) * 512 + 2 * gx;
            float2 a = *(const float2*)(p0);
            float2 b = *(const float2*)(p0 + 512);
            v = (a.x + a.y + b.x + b.y) * 0.5f;
        }
        ca[r * 70 + c] = v;
    }

    int pos = tid & 127;
    int ocg = __builtin_amdgcn_readfirstlane(tid >> 7);
    int ly = pos >> 4, lx = pos & 15;

    v2f acc2[2][2][2];
    #pragma unroll
    for (int o2 = 0; o2 < 2; ++o2)
        #pragma unroll
        for (int r = 0; r < 2; ++r)
            #pragma unroll
            for (int c = 0; c < 2; ++c) acc2[o2][r][c] = (v2f){0.f, 0.f};

    __syncthreads();   // ca ready

    #pragma unroll 1
    for (int cc = 0; cc < 4; ++cc) {
        v2f wp1[2][9];
        #pragma unroll
        for (int o2 = 0; o2 < 2; ++o2)
            #pragma unroll
            for (int k = 0; k < 9; ++k)
                wp1[o2][k] = (v2f){ w1[(cc * 4 + o2 * 2    ) * 9 + k],
                                    w1[(cc * 4 + o2 * 2 + 1) * 9 + k] };
        if (cc) __syncthreads();   // prev chunk's conv2 reads before overwrite

        // Phase a: h1 chunk = pool2(relu(conv1)), 4 oc, 18x34 (incl halo)
        #pragma unroll 1
        for (int i = tid; i < 612; i += 256) {
            int hy = i / 34, hx = i - hy * 34;
            const float* pb = ca + (2 * hy) * 70 + 2 * hx;
            v2f pr[4][2];
            #pragma unroll
            for (int r = 0; r < 4; ++r) {
                pr[r][0] = *(const v2f*)(pb + r * 70);
                pr[r][1] = *(const v2f*)(pb + r * 70 + 2);
            }
            bool oob = ((unsigned)(hy0 + hy) >= 128u) | ((unsigned)(hx0 + hx) >= 128u);
            v2f am[2][4];   // [ocpair][pos: p00 p01 p10 p11]
            #pragma unroll
            for (int ky = 0; ky < 3; ++ky)
            #pragma unroll
            for (int kx = 0; kx < 3; ++kx) {
                #pragma unroll
                for (int o2 = 0; o2 < 2; ++o2)
                #pragma unroll
                for (int dy = 0; dy < 2; ++dy)
                #pragma unroll
                for (int dx = 0; dx < 2; ++dx) {
                    v2f d = pr[ky + dy][(kx + dx) >> 1];
                    if (ky == 0 && kx == 0) {
                        if (((kx + dx) & 1) == 0) PK_MUL_W0(am[o2][dy * 2 + dx], wp1[o2][0], d);
                        else                      PK_MUL_W1(am[o2][dy * 2 + dx], wp1[o2][0], d);
                    } else {
                        if (((kx + dx) & 1) == 0) PK_FMA_W0(am[o2][dy * 2 + dx], wp1[o2][ky * 3 + kx], d);
                        else                      PK_FMA_W1(am[o2][dy * 2 + dx], wp1[o2][ky * 3 + kx], d);
                    }
                }
            }
            #pragma unroll
            for (int o2 = 0; o2 < 2; ++o2) {
                float mx = fmaxf(fmaxf(am[o2][0].x, am[o2][1].x),
                                 fmaxf(am[o2][2].x, am[o2][3].x));
                float my = fmaxf(fmaxf(am[o2][0].y, am[o2][1].y),
                                 fmaxf(am[o2][2].y, am[o2][3].y));
                mx = fmaxf(mx + b1[cc * 4 + o2 * 2    ], 0.f);
                my = fmaxf(my + b1[cc * 4 + o2 * 2 + 1], 0.f);
                h1s[((o2 * 2    ) * 18 + hy) * 34 + hx] = oob ? 0.f : mx;
                h1s[((o2 * 2 + 1) * 18 + hy) * 34 + hx] = oob ? 0.f : my;
            }
        }
        __syncthreads();

        // Phase b: conv2 accumulate over these 4 input channels (4 oc/group)
        #pragma unroll
        for (int icl = 0; icl < 4; ++icl) {
            int ic = cc * 4 + icl;
            v2f wl[2][9];   // weight pairs hoisted ahead of ds_reads
            #pragma unroll
            for (int o2 = 0; o2 < 2; ++o2) {
                int oc0 = ocg * 4 + o2 * 2;
                #pragma unroll
                for (int k = 0; k < 9; ++k)
                    wl[o2][k] = (v2f){ w2[((oc0    ) * 16 + ic) * 9 + k],
                                       w2[((oc0 + 1) * 16 + ic) * 9 + k] };
            }
            const float* base = h1s + (icl * 18 + ly * 2) * 34 + lx * 2;
            v2f wr[4][2];
            #pragma unroll
            for (int r = 0; r < 4; ++r) {
                wr[r][0] = *(const v2f*)(base + r * 34);
                wr[r][1] = *(const v2f*)(base + r * 34 + 2);
            }
            #pragma unroll
            for (int ky = 0; ky < 3; ++ky)
            #pragma unroll
            for (int kx = 0; kx < 3; ++kx)
            #pragma unroll
            for (int o2 = 0; o2 < 2; ++o2) {
                #pragma unroll
                for (int r = 0; r < 2; ++r)
                #pragma unroll
                for (int c = 0; c < 2; ++c) {
                    v2f d = wr[r + ky][(c + kx) >> 1];
                    if (((c + kx) & 1) == 0) PK_FMA_W0(acc2[o2][r][c], wl[o2][ky * 3 + kx], d);
                    else                     PK_FMA_W1(acc2[o2][r][c], wl[o2][ky * 3 + kx], d);
                }
            }
        }
    }

    // Epilogue: bias+relu+pool2 of conv2, LDS exchange, conv3 -> low
    float h2v[4];
    #pragma unroll
    for (int o2 = 0; o2 < 2; ++o2) {
        float mx = fmaxf(fmaxf(acc2[o2][0][0].x, acc2[o2][0][1].x),
                         fmaxf(acc2[o2][1][0].x, acc2[o2][1][1].x));
        float my = fmaxf(fmaxf(acc2[o2][0][0].y, acc2[o2][0][1].y),
                         fmaxf(acc2[o2][1][0].y, acc2[o2][1][1].y));
        h2v[o2 * 2    ] = fmaxf(mx + b2[ocg * 4 + o2 * 2    ], 0.f);
        h2v[o2 * 2 + 1] = fmaxf(my + b2[ocg * 4 + o2 * 2 + 1], 0.f);
    }
    __syncthreads();                 // conv2 done reading h1s; reuse for h2
    float* hx2 = h1s;                // [128 pos][9] stride 9 -> conflict-free
    #pragma unroll
    for (int j = 0; j < 4; ++j) hx2[pos * 9 + ocg * 4 + j] = h2v[j];
    __syncthreads();

    float hv[8];
    #pragma unroll
    for (int ic = 0; ic < 8; ++ic) hv[ic] = hx2[pos * 9 + ic];
    float* dst = outLow + img * 16384;
    int posg = (tyy * 8 + ly) * 64 + txx * 16 + lx;
    #pragma unroll
    for (int jo = 0; jo < 2; ++jo) {
        int oc3 = ocg * 2 + jo;
        float s = b3[oc3];
        #pragma unroll
        for (int ic = 0; ic < 8; ++ic) s += w3[oc3 * 8 + ic] * hv[ic];
        dst[oc3 * 4096 + posg] = s;
    }
}

extern "C" void kernel_launch(void* const* d_in, const int* in_sizes, int n_in,
                              void* d_out, int out_size, void* d_ws, size_t ws_size,
                              hipStream_t stream) {
    const float* x  = (const float*)d_in[0];
    const float* w1 = (const float*)d_in[1];
    const float* b1 = (const float*)d_in[2];
    const float* w2 = (const float*)d_in[3];
    const float* b2 = (const float*)d_in[4];
    const float* w3 = (const float*)d_in[5];
    const float* b3 = (const float*)d_in[6];
    float* out     = (float*)d_out;
    float* outLow  = out;                 // 1,572,864 floats
    float* outHigh = out + 1572864;       // 12,582,912 floats

    fused_all_kernel<<<3072, 256, 0, stream>>>(x, w1, b1, w2, b2, w3, b3,
                                               outLow, outHigh);
}

// Round 11
// 205.099 us; speedup vs baseline: 1.1286x; 1.0171x over previous
//
#include <hip/hip_runtime.h>

// Problem: B=32, C=3, H=512, W=512 -> NIMG = 96 flat images
// R11 structure: 512-thread blocks (8 waves). Grid 3072 (one block per 8x16
//   tile). Per CU: 4 blocks x 8 waves = 32 waves = HW occupancy cap (vs 28
//   at 256 threads), AND 12 blocks/CU over 4 slots = EXACTLY 3 full rounds
//   (100% packing; the 12-over-7 = 86% quantization of 256-thread configs
//   disappears). LDS 4 x 20,480 = 80 KB << 160 KB (wave-capped, not LDS).
// Tile body = R2/R10 proven 8x16-pooled tile, bit-identical numerics:
//   phase 0: Haar DWT -> cA 38x70 in LDS (zero-pad OOB); interior 32x64
//            cH/cV written straight to d_out high region.
//   phase a/b (x4 ic-chunks): conv1(1->16)+relu+pool2 -> LDS, conv2(16->8) acc.
//   epilogue: relu+pool2 (h2 exchange via LDS), conv3(8->4,1x1) -> d_out low.
// Thread mapping at 512: phase 0a = exactly 1 pass; conv2 = 128 pos x 4
//   wave-uniform oc-groups of 2 (acc2[2][2], one v2f pair); conv3 = exactly
//   1 output/thread, coalesced.
// R1: conv1/conv2 use v_pk_fma_f32 (packed fp32, 2 FMA/instr) over oc pairs
//   (SGPR weight pairs, free activation broadcast via VOP3P op_sel).
// R7 lesson: UNBALANCED task loops (execz-skip beats balanced-with-mask).

typedef float v2f __attribute__((ext_vector_type(2)));

// acc(pair over oc) += w(pair over oc, SGPR) * broadcast(data.word0)
#define PK_FMA_W0(acc, w, d) \
    asm("v_pk_fma_f32 %0, %1, %2, %0 op_sel:[0,0,0] op_sel_hi:[1,0,1]" \
        : "+v"(acc) : "s"(w), "v"(d))
// acc += w * broadcast(data.word1)
#define PK_FMA_W1(acc, w, d) \
    asm("v_pk_fma_f32 %0, %1, %2, %0 op_sel:[0,1,0] op_sel_hi:[1,1,1]" \
        : "+v"(acc) : "s"(w), "v"(d))
// dst = w * broadcast(data.word0)   (accumulator init without v_mov zeroing)
#define PK_MUL_W0(dst, w, d) \
    asm("v_pk_mul_f32 %0, %1, %2 op_sel:[0,0] op_sel_hi:[1,0]" \
        : "=v"(dst) : "s"(w), "v"(d))
#define PK_MUL_W1(dst, w, d) \
    asm("v_pk_mul_f32 %0, %1, %2 op_sel:[0,1] op_sel_hi:[1,1]" \
        : "=v"(dst) : "s"(w), "v"(d))

__global__ __launch_bounds__(512, 8) void fused_all_kernel(
    const float* __restrict__ x,
    const float* __restrict__ w1, const float* __restrict__ b1,
    const float* __restrict__ w2, const float* __restrict__ b2,
    const float* __restrict__ w3, const float* __restrict__ b3,
    float* __restrict__ outLow, float* __restrict__ outHigh)
{
    __shared__ __align__(16) float ca[38 * 70];      // cA tile, rows stride 70
    __shared__ __align__(16) float h1s[4 * 18 * 34]; // conv1 chunk (reused for h2 xchg)

    int tid = threadIdx.x;                 // 0..511

    int tIdx = blockIdx.x;                 // 0..3071
    int img  = tIdx >> 5;
    int t    = tIdx & 31;
    int tyy = t >> 2, txx = t & 3;         // 8 pooled rows x 16 cols
    int hy0 = tyy * 16 - 1, hx0 = txx * 32 - 1; // h1 tile origin (18x34 incl halo)
    int cy0 = tyy * 32 - 3, cx0 = txx * 64 - 3; // cA tile origin (38x70)

    const float* xi = x + img * 262144;
    float* hb = outHigh + img * 131072;

    // ---- Phase 0a: interior 32x64 cA (coalesced), cH/cV -> global ----
    // 512 tasks over 512 threads = exactly one pass.
    {
        int i = tid;
        int row = i >> 4, cg = i & 15;     // 32 rows x 16 col-groups
        int gy = tyy * 32 + row;
        int gx = txx * 64 + cg * 4;
        const float* r0 = xi + (2 * gy) * 512 + 2 * gx;
        const float* r1 = r0 + 512;
        float4 t0 = *(const float4*)(r0);
        float4 t1 = *(const float4*)(r0 + 4);
        float4 u0 = *(const float4*)(r1);
        float4 u1 = *(const float4*)(r1 + 4);
        float4 vA, vH, vV;
        vA.x = (t0.x + t0.y + u0.x + u0.y) * 0.5f;
        vH.x = (t0.x + t0.y - u0.x - u0.y) * 0.5f;
        vV.x = (t0.x - t0.y + u0.x - u0.y) * 0.5f;
        vA.y = (t0.z + t0.w + u0.z + u0.w) * 0.5f;
        vH.y = (t0.z + t0.w - u0.z - u0.w) * 0.5f;
        vV.y = (t0.z - t0.w + u0.z - u0.w) * 0.5f;
        vA.z = (t1.x + t1.y + u1.x + u1.y) * 0.5f;
        vH.z = (t1.x + t1.y - u1.x - u1.y) * 0.5f;
        vV.z = (t1.x - t1.y + u1.x - u1.y) * 0.5f;
        vA.w = (t1.z + t1.w + u1.z + u1.w) * 0.5f;
        vH.w = (t1.z + t1.w - u1.z - u1.w) * 0.5f;
        vV.w = (t1.z - t1.w + u1.z - u1.w) * 0.5f;
        int po = (gy << 8) + gx;
        *(float4*)(hb + po) = vH;
        *(float4*)(hb + 65536 + po) = vV;
        float* cp = ca + (row + 3) * 70 + cg * 4 + 3;
        cp[0] = vA.x; cp[1] = vA.y; cp[2] = vA.z; cp[3] = vA.w;
    }

    // ---- Phase 0b: 3-wide halo ring of cA (612 points), vA only ----
    // Ring = rows {0,1,2} + {35,36,37} (full width 70) + rows 3..34 with
    // cols {0,1,2,67,68,69}. Unbalanced stride-512 (execz-skips pass 2).
    #pragma unroll 1
    for (int i = tid; i < 612; i += 512) {
        int r, c;
        if (i < 210)      { r = i / 70;              c = i - r * 70; }
        else if (i < 420) { int j = i - 210; r = 35 + j / 70; c = j - (j / 70) * 70; }
        else              { int j = i - 420; r = 3 + j / 6; int k6 = j - (j / 6) * 6;
                            c = (k6 < 3) ? k6 : (64 + k6); }   // {0,1,2,67,68,69}
        int gy = cy0 + r, gx = cx0 + c;
        float v = 0.f;
        if ((unsigned)gy < 256u && (unsigned)gx < 256u) {
            const float* p0 = xi + (2 * gy) * 512 + 2 * gx;
            float2 a = *(const float2*)(p0);
            float2 b = *(const float2*)(p0 + 512);
            v = (a.x + a.y + b.x + b.y) * 0.5f;
        }
        ca[r * 70 + c] = v;
    }

    // conv2 mapping: pos = tid&127 over 8x16 pooled positions;
    // ocg = tid>>7 (0..3) picks oc pair {2*ocg, 2*ocg+1}. Wave-uniform
    // (each ocg spans exactly 2 waves).
    int pos = tid & 127;
    int ocg = __builtin_amdgcn_readfirstlane(tid >> 7);
    int ly = pos >> 4, lx = pos & 15;

    v2f acc2[2][2];                        // one oc pair x 2x2 pre-pool window
    #pragma unroll
    for (int r = 0; r < 2; ++r)
        #pragma unroll
        for (int c = 0; c < 2; ++c) acc2[r][c] = (v2f){0.f, 0.f};

    __syncthreads();   // ca ready

    #pragma unroll 1
    for (int cc = 0; cc < 4; ++cc) {
        v2f wp1[2][9];
        #pragma unroll
        for (int o2 = 0; o2 < 2; ++o2)
            #pragma unroll
            for (int k = 0; k < 9; ++k)
                wp1[o2][k] = (v2f){ w1[(cc * 4 + o2 * 2    ) * 9 + k],
                                    w1[(cc * 4 + o2 * 2 + 1) * 9 + k] };
        if (cc) __syncthreads();   // prev chunk's conv2 reads before overwrite

        // Phase a: h1 chunk = pool2(relu(conv1)), 4 oc, 18x34 (incl halo)
        // 612 tasks, stride 512: 1 full pass + 100-task partial (execz-skip).
        #pragma unroll 1
        for (int i = tid; i < 612; i += 512) {
            int hy = i / 34, hx = i - hy * 34;
            const float* pb = ca + (2 * hy) * 70 + 2 * hx;
            v2f pr[4][2];
            #pragma unroll
            for (int r = 0; r < 4; ++r) {
                pr[r][0] = *(const v2f*)(pb + r * 70);
                pr[r][1] = *(const v2f*)(pb + r * 70 + 2);
            }
            bool oob = ((unsigned)(hy0 + hy) >= 128u) | ((unsigned)(hx0 + hx) >= 128u);
            v2f am[2][4];   // [ocpair][pos: p00 p01 p10 p11]
            #pragma unroll
            for (int ky = 0; ky < 3; ++ky)
            #pragma unroll
            for (int kx = 0; kx < 3; ++kx) {
                #pragma unroll
                for (int o2 = 0; o2 < 2; ++o2)
                #pragma unroll
                for (int dy = 0; dy < 2; ++dy)
                #pragma unroll
                for (int dx = 0; dx < 2; ++dx) {
                    v2f d = pr[ky + dy][(kx + dx) >> 1];
                    if (ky == 0 && kx == 0) {
                        if (((kx + dx) & 1) == 0) PK_MUL_W0(am[o2][dy * 2 + dx], wp1[o2][0], d);
                        else                      PK_MUL_W1(am[o2][dy * 2 + dx], wp1[o2][0], d);
                    } else {
                        if (((kx + dx) & 1) == 0) PK_FMA_W0(am[o2][dy * 2 + dx], wp1[o2][ky * 3 + kx], d);
                        else                      PK_FMA_W1(am[o2][dy * 2 + dx], wp1[o2][ky * 3 + kx], d);
                    }
                }
            }
            #pragma unroll
            for (int o2 = 0; o2 < 2; ++o2) {
                float mx = fmaxf(fmaxf(am[o2][0].x, am[o2][1].x),
                                 fmaxf(am[o2][2].x, am[o2][3].x));
                float my = fmaxf(fmaxf(am[o2][0].y, am[o2][1].y),
                                 fmaxf(am[o2][2].y, am[o2][3].y));
                mx = fmaxf(mx + b1[cc * 4 + o2 * 2    ], 0.f);
                my = fmaxf(my + b1[cc * 4 + o2 * 2 + 1], 0.f);
                h1s[((o2 * 2    ) * 18 + hy) * 34 + hx] = oob ? 0.f : mx;
                h1s[((o2 * 2 + 1) * 18 + hy) * 34 + hx] = oob ? 0.f : my;
            }
        }
        __syncthreads();

        // Phase b: conv2 accumulate over these 4 input channels (2 oc/group)
        #pragma unroll
        for (int icl = 0; icl < 4; ++icl) {
            int ic = cc * 4 + icl;
            v2f wl[9];   // weight pair hoisted ahead of ds_reads
            {
                int oc0 = ocg * 2;
                #pragma unroll
                for (int k = 0; k < 9; ++k)
                    wl[k] = (v2f){ w2[((oc0    ) * 16 + ic) * 9 + k],
                                   w2[((oc0 + 1) * 16 + ic) * 9 + k] };
            }
            const float* base = h1s + (icl * 18 + ly * 2) * 34 + lx * 2;
            v2f wr[4][2];
            #pragma unroll
            for (int r = 0; r < 4; ++r) {
                wr[r][0] = *(const v2f*)(base + r * 34);
                wr[r][1] = *(const v2f*)(base + r * 34 + 2);
            }
            #pragma unroll
            for (int ky = 0; ky < 3; ++ky)
            #pragma unroll
            for (int kx = 0; kx < 3; ++kx) {
                #pragma unroll
                for (int r = 0; r < 2; ++r)
                #pragma unroll
                for (int c = 0; c < 2; ++c) {
                    v2f d = wr[r + ky][(c + kx) >> 1];
                    if (((c + kx) & 1) == 0) PK_FMA_W0(acc2[r][c], wl[ky * 3 + kx], d);
                    else                     PK_FMA_W1(acc2[r][c], wl[ky * 3 + kx], d);
                }
            }
        }
    }

    // Epilogue: bias+relu+pool2 of conv2 (2 oc/thread), LDS exchange,
    // conv3 (1x1, 8->4) -> low: exactly one output per thread, coalesced.
    float h2a, h2b;
    {
        float mx = fmaxf(fmaxf(acc2[0][0].x, acc2[0][1].x),
                         fmaxf(acc2[1][0].x, acc2[1][1].x));
        float my = fmaxf(fmaxf(acc2[0][0].y, acc2[0][1].y),
                         fmaxf(acc2[1][0].y, acc2[1][1].y));
        h2a = fmaxf(mx + b2[ocg * 2    ], 0.f);
        h2b = fmaxf(my + b2[ocg * 2 + 1], 0.f);
    }
    __syncthreads();                 // conv2 done reading h1s; reuse for h2
    float* hx2 = h1s;                // [128 pos][9] stride 9 -> conflict-free
    hx2[pos * 9 + ocg * 2    ] = h2a;
    hx2[pos * 9 + ocg * 2 + 1] = h2b;
    __syncthreads();

    float hv[8];
    #pragma unroll
    for (int ic = 0; ic < 8; ++ic) hv[ic] = hx2[pos * 9 + ic];
    float* dst = outLow + img * 16384;
    int posg = (tyy * 8 + ly) * 64 + txx * 16 + lx;
    int oc3 = ocg;                   // one conv3 output per thread
    float sacc = b3[oc3];
    #pragma unroll
    for (int ic = 0; ic < 8; ++ic) sacc += w3[oc3 * 8 + ic] * hv[ic];
    dst[oc3 * 4096 + posg] = sacc;
}

extern "C" void kernel_launch(void* const* d_in, const int* in_sizes, int n_in,
                              void* d_out, int out_size, void* d_ws, size_t ws_size,
                              hipStream_t stream) {
    const float* x  = (const float*)d_in[0];
    const float* w1 = (const float*)d_in[1];
    const float* b1 = (const float*)d_in[2];
    const float* w2 = (const float*)d_in[3];
    const float* b2 = (const float*)d_in[4];
    const float* w3 = (const float*)d_in[5];
    const float* b3 = (const float*)d_in[6];
    float* out     = (float*)d_out;
    float* outLow  = out;                 // 1,572,864 floats
    float* outHigh = out + 1572864;       // 12,582,912 floats

    fused_all_kernel<<<3072, 512, 0, stream>>>(x, w1, b1, w2, b2, w3, b3,
                                               outLow, outHigh);
}